// Round 2
// baseline (1804.935 us; speedup 1.0000x reference)
//
#include <hip/hip_runtime.h>
#include <math.h>

// Problem constants
#define N_POS     131072          // 8 * 16*32*32 positions
#define DIM       256
#define K_CODES   512
#define S_SPATIAL 16384           // 16*32*32
#define ZQ_ELEMS  33554432        // 8*256*16384
#define OUT_LOSS  33554432
#define OUT_IDXB  33554433        // idx written as float here
#define OUT_PERP  (33554433 + 131072)

// Workspace layout (bytes) — only ~2.1 KB used (safe for any ws_size)
#define WS_LOSS   0               // double
#define WS_HIST   16              // int[512]
#define WS_E2     2064            // float[512]
#define WS_FIXED  2064            // bytes zeroed (loss + hist)

// ---------------------------------------------------------------------------
// Kernel 1: codebook squared norms s_e[k], numpy-pairwise replica.
__global__ __launch_bounds__(256) void e2_kernel(const float* __restrict__ e,
                                                 float* __restrict__ e2) {
    int k = blockIdx.x * 256 + threadIdx.x;
    if (k >= K_CODES) return;
    const float* row = e + (size_t)k * DIM;
    float half[2];
#pragma unroll
    for (int h = 0; h < 2; ++h) {
        const float* base = row + h * 128;
        float r[8];
#pragma unroll
        for (int j = 0; j < 8; ++j) {
            float v = base[j];
            r[j] = __fmul_rn(v, v);
        }
        for (int i = 8; i < 128; i += 8) {
#pragma unroll
            for (int j = 0; j < 8; ++j) {
                float v = base[i + j];
                r[j] = __fadd_rn(r[j], __fmul_rn(v, v));
            }
        }
        half[h] = __fadd_rn(__fadd_rn(__fadd_rn(r[0], r[1]), __fadd_rn(r[2], r[3])),
                            __fadd_rn(__fadd_rn(r[4], r[5]), __fadd_rn(r[6], r[7])));
    }
    e2[k] = __fadd_rn(half[0], half[1]);
}

// ---------------------------------------------------------------------------
// Kernel 1b: transpose/pair codebook for lane-coalesced reads in pass1.
//   eTp[d*512 + wave*128 + lane*2 + c] = e[wave*128 + c*64 + lane][d]
// Lane (wave w) then reads its two codes {w*128+lane, w*128+64+lane} for dim d
// as ONE coalesced float2 (512 B per wave per dim).
__global__ __launch_bounds__(256) void transpose_e(const float* __restrict__ e,
                                                   float* __restrict__ eTp) {
    int t = blockIdx.x * 256 + threadIdx.x;     // t = k*256 + d, coalesced read
    int k = t >> 8;
    int d = t & 255;
    float v = e[t];
    int w = k >> 7;
    int c = (k >> 6) & 1;
    int l = k & 63;
    eTp[d * K_CODES + (w << 7) + (l << 1) + c] = v;
}

// ---------------------------------------------------------------------------
// Kernel 2: distance + argmin, lanes = codes.
// Block = 16 consecutive positions x all 512 codes (4 waves x 128 codes each;
// lane owns codes k0 = wave*128+lane and k0+64). z at dim d for the block's 16
// positions is one 64B uniform chunk -> scalar s_load; e via coalesced float2
// from eTp. Per dot: sequential fp32 FMA over d=0..255 ascending — bit-exact
// replica of the numpy computation (same as previous verified kernel).
// Argmin finishes in-block: packed (dist_bits<<32|idx) u64 min, butterfly
// shuffle across lanes, LDS across waves. First-index tie rule preserved
// (dist > 0 => float bits unsigned-monotonic; low bits idx).
__global__ __launch_bounds__(256) void pass1_dist(const float* __restrict__ z,
                                                  const float* __restrict__ eTp,
                                                  const float* __restrict__ e2,
                                                  float* __restrict__ idxf) {
    const int lane = threadIdx.x & 63;
    const int wave = threadIdx.x >> 6;          // 0..3 -> code group of 128
    const int n0   = blockIdx.x << 4;           // 16 positions per block
    const int b    = n0 >> 14;
    const float* zb = z + (size_t)b * (DIM * S_SPATIAL) + (n0 & (S_SPATIAL - 1));

    // ---- s_z for position n0 + (lane&15): exact numpy-pairwise replica ----
    // (redundant 4x across the 16-lane groups; loads are L2-hot 64B lines)
    float szv;
    {
        const float* zp = zb + (lane & 15);
        float half[2];
#pragma unroll
        for (int h = 0; h < 2; ++h) {
            const float* base = zp + (size_t)(h * 128) * S_SPATIAL;
            float r[8];
#pragma unroll
            for (int j = 0; j < 8; ++j) {
                float v = base[(size_t)j * S_SPATIAL];
                r[j] = __fmul_rn(v, v);
            }
            for (int i = 8; i < 128; i += 8) {
#pragma unroll
                for (int j = 0; j < 8; ++j) {
                    float v = base[(size_t)(i + j) * S_SPATIAL];
                    r[j] = __fadd_rn(r[j], __fmul_rn(v, v));
                }
            }
            half[h] = __fadd_rn(__fadd_rn(__fadd_rn(r[0], r[1]), __fadd_rn(r[2], r[3])),
                                __fadd_rn(__fadd_rn(r[4], r[5]), __fadd_rn(r[6], r[7])));
        }
        szv = __fadd_rn(half[0], half[1]);
    }

    const int k0 = (wave << 7) + lane;          // this lane's codes: k0, k0+64
    float se0 = e2[k0];
    float se1 = e2[k0 + 64];

    float acc0[16], acc1[16];
#pragma unroll
    for (int p = 0; p < 16; ++p) { acc0[p] = 0.f; acc1[p] = 0.f; }

    // ---- main GEMM loop: per dim, 1 float2 (e) + 16 uniform z + 32 FMA ----
    const float* ep = eTp + (wave << 7) + (lane << 1);
#pragma unroll 4
    for (int d = 0; d < DIM; ++d) {
        float2 ev = *(const float2*)(ep + (size_t)d * K_CODES);
        const float* zd = zb + ((size_t)d << 14);   // uniform 64B-aligned addr
        float zv[16];
#pragma unroll
        for (int p = 0; p < 16; ++p) zv[p] = zd[p];
#pragma unroll
        for (int p = 0; p < 16; ++p) {
            acc0[p] = __fmaf_rn(zv[p], ev.x, acc0[p]);   // sequential in d
            acc1[p] = __fmaf_rn(zv[p], ev.y, acc1[p]);
        }
    }

    // ---- argmin: pack, in-lane pair min, lane butterfly, cross-wave LDS ----
    __shared__ unsigned long long lred[4][16];
#pragma unroll
    for (int p = 0; p < 16; ++p) {
        float szp = __shfl(szv, p);
        float d0 = __fsub_rn(__fadd_rn(szp, se0), __fmul_rn(2.0f, acc0[p]));
        float d1 = __fsub_rn(__fadd_rn(szp, se1), __fmul_rn(2.0f, acc1[p]));
        unsigned long long key0 =
            ((unsigned long long)__float_as_uint(d0) << 32) | (unsigned int)k0;
        unsigned long long key1 =
            ((unsigned long long)__float_as_uint(d1) << 32) | (unsigned int)(k0 + 64);
        unsigned long long kmin = key1 < key0 ? key1 : key0;
#pragma unroll
        for (int off = 32; off; off >>= 1) {
            unsigned long long o = __shfl_xor(kmin, off);
            kmin = o < kmin ? o : kmin;
        }
        if (lane == 0) lred[wave][p] = kmin;
    }
    __syncthreads();
    if (threadIdx.x < 16) {
        int p = threadIdx.x;
        unsigned long long m01 = lred[0][p] < lred[1][p] ? lred[0][p] : lred[1][p];
        unsigned long long m23 = lred[2][p] < lred[3][p] ? lred[2][p] : lred[3][p];
        unsigned long long m   = m01 < m23 ? m01 : m23;
        idxf[n0 + p] = (float)(unsigned int)(m & 0xffffffffull);
    }
}

// ---------------------------------------------------------------------------
// Kernel 3: code-usage histogram from idxf.
__global__ __launch_bounds__(256) void hist_kernel(const float* __restrict__ idxf,
                                                   int* __restrict__ ghist) {
    __shared__ int h[K_CODES];
    for (int k = threadIdx.x; k < K_CODES; k += 256) h[k] = 0;
    __syncthreads();
    int n = blockIdx.x * 256 + threadIdx.x;           // grid covers N_POS exactly
    int idx = (int)idxf[n];
    atomicAdd(&h[idx], 1);
    __syncthreads();
    for (int k = threadIdx.x; k < K_CODES; k += 256) {
        int c = h[k];
        if (c) atomicAdd(&ghist[k], c);
    }
}

// ---------------------------------------------------------------------------
// Kernel 4: gather z_q = fl(z + fl(e[idx]-z)) + loss accumulation (double).
__global__ __launch_bounds__(256) void gather_loss(const float* __restrict__ z,
                                                   const float* __restrict__ e,
                                                   const float* __restrict__ idxf,
                                                   float* __restrict__ out,
                                                   double* __restrict__ loss) {
    int t = blockIdx.x * 256 + threadIdx.x;   // 131072 threads total
    int b   = t >> 14;
    int r   = t & 16383;
    int dg  = r >> 12;                        // 0..3 -> d range [dg*64, dg*64+64)
    int sp  = (r & 4095) << 2;                // sp multiple of 4
    int n0  = (b << 14) + sp;

    int k0 = (int)idxf[n0 + 0];
    int k1 = (int)idxf[n0 + 1];
    int k2 = (int)idxf[n0 + 2];
    int k3 = (int)idxf[n0 + 3];
    const float* e0 = e + (size_t)k0 * DIM;
    const float* e1 = e + (size_t)k1 * DIM;
    const float* e2p = e + (size_t)k2 * DIM;
    const float* e3 = e + (size_t)k3 * DIM;

    const float* zb = z + ((size_t)b * DIM << 14) + sp;
    float* ob = out + ((size_t)b * DIM << 14) + sp;

    double acc = 0.0;
    int dend = dg * 64 + 64;
    for (int d0 = dg * 64; d0 < dend; d0 += 4) {
        float4 ev0 = *(const float4*)(e0 + d0);   // components: dd=0..3 for k0
        float4 ev1 = *(const float4*)(e1 + d0);
        float4 ev2 = *(const float4*)(e2p + d0);
        float4 ev3 = *(const float4*)(e3 + d0);
#pragma unroll
        for (int dd = 0; dd < 4; ++dd) {
            size_t off = ((size_t)(d0 + dd) << 14);
            float4 zv = *(const float4*)(zb + off);
            float ea = (dd == 0) ? ev0.x : (dd == 1) ? ev0.y : (dd == 2) ? ev0.z : ev0.w;
            float eb_ = (dd == 0) ? ev1.x : (dd == 1) ? ev1.y : (dd == 2) ? ev1.z : ev1.w;
            float ec = (dd == 0) ? ev2.x : (dd == 1) ? ev2.y : (dd == 2) ? ev2.z : ev2.w;
            float ed = (dd == 0) ? ev3.x : (dd == 1) ? ev3.y : (dd == 2) ? ev3.z : ev3.w;
            float d0f = __fsub_rn(ea, zv.x);
            float d1f = __fsub_rn(eb_, zv.y);
            float d2f = __fsub_rn(ec, zv.z);
            float d3f = __fsub_rn(ed, zv.w);
            float4 ov;
            ov.x = __fadd_rn(zv.x, d0f);
            ov.y = __fadd_rn(zv.y, d1f);
            ov.z = __fadd_rn(zv.z, d2f);
            ov.w = __fadd_rn(zv.w, d3f);
            *(float4*)(ob + off) = ov;
            acc += (double)d0f * (double)d0f;
            acc += (double)d1f * (double)d1f;
            acc += (double)d2f * (double)d2f;
            acc += (double)d3f * (double)d3f;
        }
    }
    // block reduce (4 waves)
    for (int off = 32; off; off >>= 1) acc += __shfl_down(acc, off);
    __shared__ double red[4];
    if ((threadIdx.x & 63) == 0) red[threadIdx.x >> 6] = acc;
    __syncthreads();
    if (threadIdx.x == 0) {
        double tsum = red[0] + red[1] + red[2] + red[3];
        atomicAdd(loss, tsum);
    }
}

// ---------------------------------------------------------------------------
// Kernel 5: finalize vq_loss and perplexity. 1 block, 512 threads.
__global__ __launch_bounds__(512) void finalize_kernel(const int* __restrict__ ghist,
                                                       const double* __restrict__ loss,
                                                       float* __restrict__ out) {
    int k = threadIdx.x;
    double p = (double)ghist[k] / (double)N_POS;
    double t = p * log(p + 1e-10);
    for (int off = 32; off; off >>= 1) t += __shfl_down(t, off);
    __shared__ double red[8];
    if ((k & 63) == 0) red[k >> 6] = t;
    __syncthreads();
    if (k == 0) {
        double sum = 0.0;
        for (int i = 0; i < 8; ++i) sum += red[i];
        double perp = exp(-sum);
        double mse  = (*loss) / (double)ZQ_ELEMS;
        out[OUT_LOSS] = (float)(1.25 * mse);   // codebook + 0.25*commit, same MSE
        out[OUT_PERP] = (float)perp;
    }
}

// ---------------------------------------------------------------------------
extern "C" void kernel_launch(void* const* d_in, const int* in_sizes, int n_in,
                              void* d_out, int out_size, void* d_ws, size_t ws_size,
                              hipStream_t stream) {
    const float* z = (const float*)d_in[0];
    const float* e = (const float*)d_in[1];
    float* out = (float*)d_out;
    char* ws = (char*)d_ws;

    double* loss  = (double*)(ws + WS_LOSS);
    int*    ghist = (int*)(ws + WS_HIST);
    float*  e2    = (float*)(ws + WS_E2);
    float*  idxf  = out + OUT_IDXB;

    // Transposed codebook scratch lives at the start of the z_q output region
    // (512 KB; overwritten by gather_loss afterwards) — no ws_size assumption.
    float* eTp = (float*)d_out;

    hipMemsetAsync(d_ws, 0, WS_FIXED, stream);                 // loss + hist = 0

    e2_kernel      <<<2, 256, 0, stream>>>(e, e2);
    transpose_e    <<<512, 256, 0, stream>>>(e, eTp);
    pass1_dist     <<<N_POS / 16, 256, 0, stream>>>(z, eTp, e2, idxf);
    hist_kernel    <<<N_POS / 256, 256, 0, stream>>>(idxf, ghist);
    gather_loss    <<<N_POS / 256, 256, 0, stream>>>(z, e, idxf, out, loss);
    finalize_kernel<<<1, 512, 0, stream>>>(ghist, loss, out);
}

// Round 3
// 735.550 us; speedup vs baseline: 2.4539x; 2.4539x over previous
//
#include <hip/hip_runtime.h>
#include <math.h>

// Problem constants
#define N_POS     131072          // 8 * 16*32*32 positions
#define DIM       256
#define K_CODES   512
#define S_SPATIAL 16384           // 16*32*32
#define ZQ_ELEMS  33554432        // 8*256*16384
#define OUT_LOSS  33554432
#define OUT_IDXB  33554433        // idx written as float here
#define OUT_PERP  (33554433 + 131072)

// Workspace layout (bytes) — only ~2.1 KB used (safe for any ws_size)
#define WS_LOSS   0               // double
#define WS_HIST   16              // int[512]
#define WS_E2     2064            // float[512]
#define WS_FIXED  2064            // bytes zeroed (loss + hist)

// ---------------------------------------------------------------------------
// Kernel 1: codebook squared norms s_e[k], numpy-pairwise replica.
__global__ __launch_bounds__(256) void e2_kernel(const float* __restrict__ e,
                                                 float* __restrict__ e2) {
    int k = blockIdx.x * 256 + threadIdx.x;
    if (k >= K_CODES) return;
    const float* row = e + (size_t)k * DIM;
    float half[2];
#pragma unroll
    for (int h = 0; h < 2; ++h) {
        const float* base = row + h * 128;
        float r[8];
#pragma unroll
        for (int j = 0; j < 8; ++j) {
            float v = base[j];
            r[j] = __fmul_rn(v, v);
        }
        for (int i = 8; i < 128; i += 8) {
#pragma unroll
            for (int j = 0; j < 8; ++j) {
                float v = base[i + j];
                r[j] = __fadd_rn(r[j], __fmul_rn(v, v));
            }
        }
        half[h] = __fadd_rn(__fadd_rn(__fadd_rn(r[0], r[1]), __fadd_rn(r[2], r[3])),
                            __fadd_rn(__fadd_rn(r[4], r[5]), __fadd_rn(r[6], r[7])));
    }
    e2[k] = __fadd_rn(half[0], half[1]);
}

// ---------------------------------------------------------------------------
// Kernel 1b: transpose/pair codebook for lane-coalesced reads in pass1.
//   eTp[d*512 + wave*128 + lane*2 + c] = e[wave*128 + c*64 + lane][d]
__global__ __launch_bounds__(256) void transpose_e(const float* __restrict__ e,
                                                   float* __restrict__ eTp) {
    int t = blockIdx.x * 256 + threadIdx.x;     // t = k*256 + d, coalesced read
    int k = t >> 8;
    int d = t & 255;
    float v = e[t];
    int w = k >> 7;
    int c = (k >> 6) & 1;
    int l = k & 63;
    eTp[d * K_CODES + (w << 7) + (l << 1) + c] = v;
}

// ---------------------------------------------------------------------------
// Kernel 1c: s_z[n] = numpy-pairwise sum of z[n,d]^2. Thread = position,
// lane-coalesced strided loads (the baseline-verified access pattern).
// Bit-exact: same tree, same order as the reference/baseline.
__global__ __launch_bounds__(256) void sz_kernel(const float* __restrict__ z,
                                                 float* __restrict__ sz) {
    int n = blockIdx.x * 256 + threadIdx.x;
    int b = n >> 14;
    int s = n & (S_SPATIAL - 1);
    const float* zp = z + (size_t)b * (DIM * S_SPATIAL) + s;
    float half[2];
#pragma unroll
    for (int h = 0; h < 2; ++h) {
        const float* base = zp + (size_t)(h * 128) * S_SPATIAL;
        float r[8];
#pragma unroll
        for (int j = 0; j < 8; ++j) {
            float v = base[(size_t)j * S_SPATIAL];
            r[j] = __fmul_rn(v, v);
        }
        for (int i = 8; i < 128; i += 8) {
#pragma unroll
            for (int j = 0; j < 8; ++j) {
                float v = base[(size_t)(i + j) * S_SPATIAL];
                r[j] = __fadd_rn(r[j], __fmul_rn(v, v));
            }
        }
        half[h] = __fadd_rn(__fadd_rn(__fadd_rn(r[0], r[1]), __fadd_rn(r[2], r[3])),
                            __fadd_rn(__fadd_rn(r[4], r[5]), __fadd_rn(r[6], r[7])));
    }
    sz[n] = __fadd_rn(half[0], half[1]);
}

// ---------------------------------------------------------------------------
// Kernel 2: distance + argmin, lanes = codes, z staged in LDS.
// Block = 16 positions x all 512 codes (4 waves x 128 codes; lane owns codes
// k0 = wave*128+lane and k0+64). The block's z slice (256d x 16pos = 16 KB)
// is staged into LDS once (coalesced global loads), then read per-d as 4
// broadcast ds_read_b128 (uniform address -> conflict-free). Per dot:
// sequential fp32 FMA over d=0..255 ascending — bit-exact numpy replica
// (identical math to the round-2 PASSED kernel; only the z data path moved
// global->LDS, value-preserving). Argmin: packed (dist_bits<<32|idx) u64 min,
// lane butterfly + cross-wave LDS; first-index tie rule preserved.
__global__ __launch_bounds__(256) void pass1_dist(const float* __restrict__ z,
                                                  const float* __restrict__ eTp,
                                                  const float* __restrict__ e2,
                                                  const float* __restrict__ sz,
                                                  float* __restrict__ idxf) {
    const int lane = threadIdx.x & 63;
    const int wave = threadIdx.x >> 6;          // 0..3 -> code group of 128
    const int n0   = blockIdx.x << 4;           // 16 positions per block
    const int b    = n0 >> 14;
    const float* zb = z + (size_t)b * (DIM * S_SPATIAL) + (n0 & (S_SPATIAL - 1));

    __shared__ float zs[DIM][16];               // 16 KB
    __shared__ unsigned long long lred[4][16];  // 512 B

    // ---- cooperative z stage: 1024 float4s, line-granular coalescing ----
    for (int j = threadIdx.x; j < 1024; j += 256) {
        int d  = j >> 2;
        int p4 = (j & 3) << 2;
        float4 v = *(const float4*)(zb + ((size_t)d << 14) + p4);
        *(float4*)(&zs[d][p4]) = v;
    }

    float szv = sz[n0 + (lane & 15)];           // lane p<16 holds sz[n0+p]

    const int k0 = (wave << 7) + lane;          // this lane's codes: k0, k0+64
    float se0 = e2[k0];
    float se1 = e2[k0 + 64];

    float acc0[16], acc1[16];
#pragma unroll
    for (int p = 0; p < 16; ++p) { acc0[p] = 0.f; acc1[p] = 0.f; }

    __syncthreads();

    // ---- main loop: per dim, 1 float2 (eTp, L2) + 4 broadcast ds_read_b128
    //      + 32 FMAs. Sequential in d per accumulator. ----
    const float* ep = eTp + (wave << 7) + (lane << 1);
#pragma unroll 2
    for (int d = 0; d < DIM; ++d) {
        float2 ev = *(const float2*)(ep + (size_t)d * K_CODES);
        float zv[16];
        *(float4*)(zv +  0) = *(const float4*)(&zs[d][ 0]);
        *(float4*)(zv +  4) = *(const float4*)(&zs[d][ 4]);
        *(float4*)(zv +  8) = *(const float4*)(&zs[d][ 8]);
        *(float4*)(zv + 12) = *(const float4*)(&zs[d][12]);
#pragma unroll
        for (int p = 0; p < 16; ++p) {
            acc0[p] = __fmaf_rn(zv[p], ev.x, acc0[p]);
            acc1[p] = __fmaf_rn(zv[p], ev.y, acc1[p]);
        }
    }

    // ---- argmin: pack, in-lane pair min, lane butterfly, cross-wave LDS ----
#pragma unroll
    for (int p = 0; p < 16; ++p) {
        float szp = __shfl(szv, p);
        float d0 = __fsub_rn(__fadd_rn(szp, se0), __fmul_rn(2.0f, acc0[p]));
        float d1 = __fsub_rn(__fadd_rn(szp, se1), __fmul_rn(2.0f, acc1[p]));
        unsigned long long key0 =
            ((unsigned long long)__float_as_uint(d0) << 32) | (unsigned int)k0;
        unsigned long long key1 =
            ((unsigned long long)__float_as_uint(d1) << 32) | (unsigned int)(k0 + 64);
        unsigned long long kmin = key1 < key0 ? key1 : key0;
#pragma unroll
        for (int off = 32; off; off >>= 1) {
            unsigned long long o = __shfl_xor(kmin, off);
            kmin = o < kmin ? o : kmin;
        }
        if (lane == 0) lred[wave][p] = kmin;
    }
    __syncthreads();
    if (threadIdx.x < 16) {
        int p = threadIdx.x;
        unsigned long long m01 = lred[0][p] < lred[1][p] ? lred[0][p] : lred[1][p];
        unsigned long long m23 = lred[2][p] < lred[3][p] ? lred[2][p] : lred[3][p];
        unsigned long long m   = m01 < m23 ? m01 : m23;
        idxf[n0 + p] = (float)(unsigned int)(m & 0xffffffffull);
    }
}

// ---------------------------------------------------------------------------
// Kernel 3: code-usage histogram from idxf.
__global__ __launch_bounds__(256) void hist_kernel(const float* __restrict__ idxf,
                                                   int* __restrict__ ghist) {
    __shared__ int h[K_CODES];
    for (int k = threadIdx.x; k < K_CODES; k += 256) h[k] = 0;
    __syncthreads();
    int n = blockIdx.x * 256 + threadIdx.x;           // grid covers N_POS exactly
    int idx = (int)idxf[n];
    atomicAdd(&h[idx], 1);
    __syncthreads();
    for (int k = threadIdx.x; k < K_CODES; k += 256) {
        int c = h[k];
        if (c) atomicAdd(&ghist[k], c);
    }
}

// ---------------------------------------------------------------------------
// Kernel 4: gather z_q = fl(z + fl(e[idx]-z)) + loss accumulation (double).
__global__ __launch_bounds__(256) void gather_loss(const float* __restrict__ z,
                                                   const float* __restrict__ e,
                                                   const float* __restrict__ idxf,
                                                   float* __restrict__ out,
                                                   double* __restrict__ loss) {
    int t = blockIdx.x * 256 + threadIdx.x;   // 131072 threads total
    int b   = t >> 14;
    int r   = t & 16383;
    int dg  = r >> 12;                        // 0..3 -> d range [dg*64, dg*64+64)
    int sp  = (r & 4095) << 2;                // sp multiple of 4
    int n0  = (b << 14) + sp;

    int k0 = (int)idxf[n0 + 0];
    int k1 = (int)idxf[n0 + 1];
    int k2 = (int)idxf[n0 + 2];
    int k3 = (int)idxf[n0 + 3];
    const float* e0 = e + (size_t)k0 * DIM;
    const float* e1 = e + (size_t)k1 * DIM;
    const float* e2p = e + (size_t)k2 * DIM;
    const float* e3 = e + (size_t)k3 * DIM;

    const float* zb = z + ((size_t)b * DIM << 14) + sp;
    float* ob = out + ((size_t)b * DIM << 14) + sp;

    double acc = 0.0;
    int dend = dg * 64 + 64;
    for (int d0 = dg * 64; d0 < dend; d0 += 4) {
        float4 ev0 = *(const float4*)(e0 + d0);   // components: dd=0..3 for k0
        float4 ev1 = *(const float4*)(e1 + d0);
        float4 ev2 = *(const float4*)(e2p + d0);
        float4 ev3 = *(const float4*)(e3 + d0);
#pragma unroll
        for (int dd = 0; dd < 4; ++dd) {
            size_t off = ((size_t)(d0 + dd) << 14);
            float4 zv = *(const float4*)(zb + off);
            float ea = (dd == 0) ? ev0.x : (dd == 1) ? ev0.y : (dd == 2) ? ev0.z : ev0.w;
            float eb_ = (dd == 0) ? ev1.x : (dd == 1) ? ev1.y : (dd == 2) ? ev1.z : ev1.w;
            float ec = (dd == 0) ? ev2.x : (dd == 1) ? ev2.y : (dd == 2) ? ev2.z : ev2.w;
            float ed = (dd == 0) ? ev3.x : (dd == 1) ? ev3.y : (dd == 2) ? ev3.z : ev3.w;
            float d0f = __fsub_rn(ea, zv.x);
            float d1f = __fsub_rn(eb_, zv.y);
            float d2f = __fsub_rn(ec, zv.z);
            float d3f = __fsub_rn(ed, zv.w);
            float4 ov;
            ov.x = __fadd_rn(zv.x, d0f);
            ov.y = __fadd_rn(zv.y, d1f);
            ov.z = __fadd_rn(zv.z, d2f);
            ov.w = __fadd_rn(zv.w, d3f);
            *(float4*)(ob + off) = ov;
            acc += (double)d0f * (double)d0f;
            acc += (double)d1f * (double)d1f;
            acc += (double)d2f * (double)d2f;
            acc += (double)d3f * (double)d3f;
        }
    }
    // block reduce (4 waves)
    for (int off = 32; off; off >>= 1) acc += __shfl_down(acc, off);
    __shared__ double red[4];
    if ((threadIdx.x & 63) == 0) red[threadIdx.x >> 6] = acc;
    __syncthreads();
    if (threadIdx.x == 0) {
        double tsum = red[0] + red[1] + red[2] + red[3];
        atomicAdd(loss, tsum);
    }
}

// ---------------------------------------------------------------------------
// Kernel 5: finalize vq_loss and perplexity. 1 block, 512 threads.
__global__ __launch_bounds__(512) void finalize_kernel(const int* __restrict__ ghist,
                                                       const double* __restrict__ loss,
                                                       float* __restrict__ out) {
    int k = threadIdx.x;
    double p = (double)ghist[k] / (double)N_POS;
    double t = p * log(p + 1e-10);
    for (int off = 32; off; off >>= 1) t += __shfl_down(t, off);
    __shared__ double red[8];
    if ((k & 63) == 0) red[k >> 6] = t;
    __syncthreads();
    if (k == 0) {
        double sum = 0.0;
        for (int i = 0; i < 8; ++i) sum += red[i];
        double perp = exp(-sum);
        double mse  = (*loss) / (double)ZQ_ELEMS;
        out[OUT_LOSS] = (float)(1.25 * mse);   // codebook + 0.25*commit, same MSE
        out[OUT_PERP] = (float)perp;
    }
}

// ---------------------------------------------------------------------------
extern "C" void kernel_launch(void* const* d_in, const int* in_sizes, int n_in,
                              void* d_out, int out_size, void* d_ws, size_t ws_size,
                              hipStream_t stream) {
    const float* z = (const float*)d_in[0];
    const float* e = (const float*)d_in[1];
    float* out = (float*)d_out;
    char* ws = (char*)d_ws;

    double* loss  = (double*)(ws + WS_LOSS);
    int*    ghist = (int*)(ws + WS_HIST);
    float*  e2    = (float*)(ws + WS_E2);
    float*  idxf  = out + OUT_IDXB;

    // Scratch in the z_q output region (overwritten by gather_loss later,
    // which runs after all readers): eTp = 512 KB, sz = 512 KB.
    float* eTp = (float*)d_out;                     // 131072 floats
    float* szp = (float*)d_out + 131072;            // 131072 floats

    hipMemsetAsync(d_ws, 0, WS_FIXED, stream);      // loss + hist = 0

    e2_kernel      <<<2, 256, 0, stream>>>(e, e2);
    transpose_e    <<<512, 256, 0, stream>>>(e, eTp);
    sz_kernel      <<<N_POS / 256, 256, 0, stream>>>(z, szp);
    pass1_dist     <<<N_POS / 16, 256, 0, stream>>>(z, eTp, e2, szp, idxf);
    hist_kernel    <<<N_POS / 256, 256, 0, stream>>>(idxf, ghist);
    gather_loss    <<<N_POS / 256, 256, 0, stream>>>(z, e, idxf, out, loss);
    finalize_kernel<<<1, 512, 0, stream>>>(ghist, loss, out);
}

// Round 4
// 685.263 us; speedup vs baseline: 2.6339x; 1.0734x over previous
//
#include <hip/hip_runtime.h>
#include <math.h>

// Problem constants
#define N_POS     131072          // 8 * 16*32*32 positions
#define DIM       256
#define K_CODES   512
#define S_SPATIAL 16384           // 16*32*32
#define ZQ_ELEMS  33554432        // 8*256*16384
#define OUT_LOSS  33554432
#define OUT_IDXB  33554433        // idx written as float here
#define OUT_PERP  (33554433 + 131072)

// Workspace layout (bytes) — only ~2.1 KB used (safe for any ws_size)
#define WS_LOSS   0               // double
#define WS_HIST   16              // int[512]
#define WS_E2     2064            // float[512]
#define WS_FIXED  2064            // bytes zeroed (loss + hist)

// ---------------------------------------------------------------------------
// Kernel 1: codebook squared norms s_e[k], numpy-pairwise replica.
__global__ __launch_bounds__(256) void e2_kernel(const float* __restrict__ e,
                                                 float* __restrict__ e2) {
    int k = blockIdx.x * 256 + threadIdx.x;
    if (k >= K_CODES) return;
    const float* row = e + (size_t)k * DIM;
    float half[2];
#pragma unroll
    for (int h = 0; h < 2; ++h) {
        const float* base = row + h * 128;
        float r[8];
#pragma unroll
        for (int j = 0; j < 8; ++j) {
            float v = base[j];
            r[j] = __fmul_rn(v, v);
        }
        for (int i = 8; i < 128; i += 8) {
#pragma unroll
            for (int j = 0; j < 8; ++j) {
                float v = base[i + j];
                r[j] = __fadd_rn(r[j], __fmul_rn(v, v));
            }
        }
        half[h] = __fadd_rn(__fadd_rn(__fadd_rn(r[0], r[1]), __fadd_rn(r[2], r[3])),
                            __fadd_rn(__fadd_rn(r[4], r[5]), __fadd_rn(r[6], r[7])));
    }
    e2[k] = __fadd_rn(half[0], half[1]);
}

// ---------------------------------------------------------------------------
// Kernel 1b: transpose codebook to float4-per-lane layout for pass1.
// Lane (w,l) owns codes k_c = c*128 + w*64 + l, c=0..3. For dim d it reads
// eTq[((d*2 + w)*64 + l)*4 + c] as ONE float4 (1 KB contiguous per wave).
__global__ __launch_bounds__(256) void transpose_e(const float* __restrict__ e,
                                                   float* __restrict__ eTq) {
    int t = blockIdx.x * 256 + threadIdx.x;     // t = k*256 + d, coalesced read
    int k = t >> 8;
    int d = t & 255;
    float v = e[t];
    int c = k >> 7;
    int w = (k >> 6) & 1;
    int l = k & 63;
    eTq[(((d << 1) + w) << 8) + (l << 2) + c] = v;
}

// ---------------------------------------------------------------------------
// Kernel 1c: s_z[n] = numpy-pairwise sum of z[n,d]^2. Thread = position,
// lane-coalesced strided loads. Bit-exact: same tree/order as reference.
__global__ __launch_bounds__(256) void sz_kernel(const float* __restrict__ z,
                                                 float* __restrict__ sz) {
    int n = blockIdx.x * 256 + threadIdx.x;
    int b = n >> 14;
    int s = n & (S_SPATIAL - 1);
    const float* zp = z + (size_t)b * (DIM * S_SPATIAL) + s;
    float half[2];
#pragma unroll
    for (int h = 0; h < 2; ++h) {
        const float* base = zp + (size_t)(h * 128) * S_SPATIAL;
        float r[8];
#pragma unroll
        for (int j = 0; j < 8; ++j) {
            float v = base[(size_t)j * S_SPATIAL];
            r[j] = __fmul_rn(v, v);
        }
        for (int i = 8; i < 128; i += 8) {
#pragma unroll
            for (int j = 0; j < 8; ++j) {
                float v = base[(size_t)(i + j) * S_SPATIAL];
                r[j] = __fadd_rn(r[j], __fmul_rn(v, v));
            }
        }
        half[h] = __fadd_rn(__fadd_rn(__fadd_rn(r[0], r[1]), __fadd_rn(r[2], r[3])),
                            __fadd_rn(__fadd_rn(r[4], r[5]), __fadd_rn(r[6], r[7])));
    }
    sz[n] = __fadd_rn(half[0], half[1]);
}

// ---------------------------------------------------------------------------
// Kernel 2: distance + argmin. Block = 128 threads (2 waves) x 16 positions.
// Lane owns C=4 codes (c*128 + wave*64 + lane); block covers all 512 codes.
// z slice (256d x 16pos = 16 KB) staged in LDS, read per-d as 4 broadcast
// ds_read_b128 (uniform addr, conflict-free); each z delivery now feeds 4
// FMAs (was 2) -> LDS->VGPR delivery traffic halves to ~17 GB ~= FMA floor.
// e via one coalesced float4 per lane per d. Per dot: sequential fp32 FMA
// over d=0..255 ascending — bit-exact numpy replica (identical math to the
// round-3 PASSED kernel). Argmin: packed (dist_bits<<32|idx) u64 min over
// c (ascending idx), lane butterfly, cross-wave LDS; first-index ties kept.
// Histogram fused into the tail (saves a kernel + 0.5 MB re-read).
__global__ __launch_bounds__(128, 4) void pass1_dist(const float* __restrict__ z,
                                                     const float* __restrict__ eTq,
                                                     const float* __restrict__ e2,
                                                     const float* __restrict__ sz,
                                                     float* __restrict__ idxf,
                                                     int* __restrict__ ghist) {
    const int lane = threadIdx.x & 63;
    const int wave = threadIdx.x >> 6;          // 0..1
    const int n0   = blockIdx.x << 4;           // 16 positions per block
    const int b    = n0 >> 14;
    const float* zb = z + (size_t)b * (DIM * S_SPATIAL) + (n0 & (S_SPATIAL - 1));

    __shared__ float zs[DIM][16];               // 16 KB
    __shared__ unsigned long long lred[2][16];  // 256 B

    // ---- cooperative z stage: 1024 float4s, full-line coalescing ----
    for (int j = threadIdx.x; j < 1024; j += 128) {
        int d  = j >> 2;
        int p4 = (j & 3) << 2;
        float4 v = *(const float4*)(zb + ((size_t)d << 14) + p4);
        *(float4*)(&zs[d][p4]) = v;
    }

    float szv = sz[n0 + (lane & 15)];           // lane p<16 holds sz[n0+p]

    const int kbase = (wave << 6) + lane;       // codes kbase + c*128, c=0..3
    float se0 = e2[kbase];
    float se1 = e2[kbase + 128];
    float se2 = e2[kbase + 256];
    float se3 = e2[kbase + 384];

    float a0[16], a1[16], a2[16], a3[16];
#pragma unroll
    for (int p = 0; p < 16; ++p) { a0[p] = 0.f; a1[p] = 0.f; a2[p] = 0.f; a3[p] = 0.f; }

    __syncthreads();

    // ---- main loop: per dim, 1 float4 (eTq, L2) + 4 broadcast ds_read_b128
    //      + 64 FMAs. Each accumulator: one FMA per d, ascending. ----
    const float* ep = eTq + (size_t)(((wave << 6) + lane) << 2);
#pragma unroll 2
    for (int d = 0; d < DIM; ++d) {
        float4 ev = *(const float4*)(ep + ((size_t)d << 9));
        float zv[16];
        *(float4*)(zv +  0) = *(const float4*)(&zs[d][ 0]);
        *(float4*)(zv +  4) = *(const float4*)(&zs[d][ 4]);
        *(float4*)(zv +  8) = *(const float4*)(&zs[d][ 8]);
        *(float4*)(zv + 12) = *(const float4*)(&zs[d][12]);
#pragma unroll
        for (int p = 0; p < 16; ++p) {
            a0[p] = __fmaf_rn(zv[p], ev.x, a0[p]);
            a1[p] = __fmaf_rn(zv[p], ev.y, a1[p]);
            a2[p] = __fmaf_rn(zv[p], ev.z, a2[p]);
            a3[p] = __fmaf_rn(zv[p], ev.w, a3[p]);
        }
    }

    // ---- argmin: pack, in-lane min over c (ascending idx), lane butterfly,
    //      cross-wave LDS; fused histogram ----
#pragma unroll
    for (int p = 0; p < 16; ++p) {
        float szp = __shfl(szv, p);
        float d0 = __fsub_rn(__fadd_rn(szp, se0), __fmul_rn(2.0f, a0[p]));
        float d1 = __fsub_rn(__fadd_rn(szp, se1), __fmul_rn(2.0f, a1[p]));
        float d2 = __fsub_rn(__fadd_rn(szp, se2), __fmul_rn(2.0f, a2[p]));
        float d3 = __fsub_rn(__fadd_rn(szp, se3), __fmul_rn(2.0f, a3[p]));
        unsigned long long k0 =
            ((unsigned long long)__float_as_uint(d0) << 32) | (unsigned int)(kbase);
        unsigned long long k1 =
            ((unsigned long long)__float_as_uint(d1) << 32) | (unsigned int)(kbase + 128);
        unsigned long long k2 =
            ((unsigned long long)__float_as_uint(d2) << 32) | (unsigned int)(kbase + 256);
        unsigned long long k3 =
            ((unsigned long long)__float_as_uint(d3) << 32) | (unsigned int)(kbase + 384);
        unsigned long long m01 = k1 < k0 ? k1 : k0;
        unsigned long long m23 = k3 < k2 ? k3 : k2;
        unsigned long long kmin = m23 < m01 ? m23 : m01;
#pragma unroll
        for (int off = 32; off; off >>= 1) {
            unsigned long long o = __shfl_xor(kmin, off);
            kmin = o < kmin ? o : kmin;
        }
        if (lane == 0) lred[wave][p] = kmin;
    }
    __syncthreads();
    if (threadIdx.x < 16) {
        int p = threadIdx.x;
        unsigned long long m = lred[0][p] < lred[1][p] ? lred[0][p] : lred[1][p];
        int idx = (int)(unsigned int)(m & 0xffffffffull);
        idxf[n0 + p] = (float)idx;
        atomicAdd(&ghist[idx], 1);
    }
}

// ---------------------------------------------------------------------------
// Kernel 4: gather z_q = fl(z + fl(e[idx]-z)) + loss accumulation (double).
__global__ __launch_bounds__(256) void gather_loss(const float* __restrict__ z,
                                                   const float* __restrict__ e,
                                                   const float* __restrict__ idxf,
                                                   float* __restrict__ out,
                                                   double* __restrict__ loss) {
    int t = blockIdx.x * 256 + threadIdx.x;   // 131072 threads total
    int b   = t >> 14;
    int r   = t & 16383;
    int dg  = r >> 12;                        // 0..3 -> d range [dg*64, dg*64+64)
    int sp  = (r & 4095) << 2;                // sp multiple of 4
    int n0  = (b << 14) + sp;

    int k0 = (int)idxf[n0 + 0];
    int k1 = (int)idxf[n0 + 1];
    int k2 = (int)idxf[n0 + 2];
    int k3 = (int)idxf[n0 + 3];
    const float* e0 = e + (size_t)k0 * DIM;
    const float* e1 = e + (size_t)k1 * DIM;
    const float* e2p = e + (size_t)k2 * DIM;
    const float* e3 = e + (size_t)k3 * DIM;

    const float* zb = z + ((size_t)b * DIM << 14) + sp;
    float* ob = out + ((size_t)b * DIM << 14) + sp;

    double acc = 0.0;
    int dend = dg * 64 + 64;
    for (int d0 = dg * 64; d0 < dend; d0 += 4) {
        float4 ev0 = *(const float4*)(e0 + d0);   // components: dd=0..3 for k0
        float4 ev1 = *(const float4*)(e1 + d0);
        float4 ev2 = *(const float4*)(e2p + d0);
        float4 ev3 = *(const float4*)(e3 + d0);
#pragma unroll
        for (int dd = 0; dd < 4; ++dd) {
            size_t off = ((size_t)(d0 + dd) << 14);
            float4 zv = *(const float4*)(zb + off);
            float ea = (dd == 0) ? ev0.x : (dd == 1) ? ev0.y : (dd == 2) ? ev0.z : ev0.w;
            float eb_ = (dd == 0) ? ev1.x : (dd == 1) ? ev1.y : (dd == 2) ? ev1.z : ev1.w;
            float ec = (dd == 0) ? ev2.x : (dd == 1) ? ev2.y : (dd == 2) ? ev2.z : ev2.w;
            float ed = (dd == 0) ? ev3.x : (dd == 1) ? ev3.y : (dd == 2) ? ev3.z : ev3.w;
            float d0f = __fsub_rn(ea, zv.x);
            float d1f = __fsub_rn(eb_, zv.y);
            float d2f = __fsub_rn(ec, zv.z);
            float d3f = __fsub_rn(ed, zv.w);
            float4 ov;
            ov.x = __fadd_rn(zv.x, d0f);
            ov.y = __fadd_rn(zv.y, d1f);
            ov.z = __fadd_rn(zv.z, d2f);
            ov.w = __fadd_rn(zv.w, d3f);
            *(float4*)(ob + off) = ov;
            acc += (double)d0f * (double)d0f;
            acc += (double)d1f * (double)d1f;
            acc += (double)d2f * (double)d2f;
            acc += (double)d3f * (double)d3f;
        }
    }
    // block reduce (4 waves)
    for (int off = 32; off; off >>= 1) acc += __shfl_down(acc, off);
    __shared__ double red[4];
    if ((threadIdx.x & 63) == 0) red[threadIdx.x >> 6] = acc;
    __syncthreads();
    if (threadIdx.x == 0) {
        double tsum = red[0] + red[1] + red[2] + red[3];
        atomicAdd(loss, tsum);
    }
}

// ---------------------------------------------------------------------------
// Kernel 5: finalize vq_loss and perplexity. 1 block, 512 threads.
__global__ __launch_bounds__(512) void finalize_kernel(const int* __restrict__ ghist,
                                                       const double* __restrict__ loss,
                                                       float* __restrict__ out) {
    int k = threadIdx.x;
    double p = (double)ghist[k] / (double)N_POS;
    double t = p * log(p + 1e-10);
    for (int off = 32; off; off >>= 1) t += __shfl_down(t, off);
    __shared__ double red[8];
    if ((k & 63) == 0) red[k >> 6] = t;
    __syncthreads();
    if (k == 0) {
        double sum = 0.0;
        for (int i = 0; i < 8; ++i) sum += red[i];
        double perp = exp(-sum);
        double mse  = (*loss) / (double)ZQ_ELEMS;
        out[OUT_LOSS] = (float)(1.25 * mse);   // codebook + 0.25*commit, same MSE
        out[OUT_PERP] = (float)perp;
    }
}

// ---------------------------------------------------------------------------
extern "C" void kernel_launch(void* const* d_in, const int* in_sizes, int n_in,
                              void* d_out, int out_size, void* d_ws, size_t ws_size,
                              hipStream_t stream) {
    const float* z = (const float*)d_in[0];
    const float* e = (const float*)d_in[1];
    float* out = (float*)d_out;
    char* ws = (char*)d_ws;

    double* loss  = (double*)(ws + WS_LOSS);
    int*    ghist = (int*)(ws + WS_HIST);
    float*  e2    = (float*)(ws + WS_E2);
    float*  idxf  = out + OUT_IDXB;

    // Scratch in the z_q output region (overwritten by gather_loss later,
    // which runs after all readers): eTq = 512 KB, sz = 512 KB.
    float* eTq = (float*)d_out;                     // 131072 floats
    float* szp = (float*)d_out + 131072;            // 131072 floats

    hipMemsetAsync(d_ws, 0, WS_FIXED, stream);      // loss + hist = 0

    e2_kernel      <<<2, 256, 0, stream>>>(e, e2);
    transpose_e    <<<512, 256, 0, stream>>>(e, eTq);
    sz_kernel      <<<N_POS / 256, 256, 0, stream>>>(z, szp);
    pass1_dist     <<<N_POS / 16, 128, 0, stream>>>(z, eTq, e2, szp, idxf, ghist);
    gather_loss    <<<N_POS / 256, 256, 0, stream>>>(z, e, idxf, out, loss);
    finalize_kernel<<<1, 512, 0, stream>>>(ghist, loss, out);
}

// Round 5
// 677.132 us; speedup vs baseline: 2.6656x; 1.0120x over previous
//
#include <hip/hip_runtime.h>
#include <math.h>

// Problem constants
#define N_POS     131072          // 8 * 16*32*32 positions
#define DIM       256
#define K_CODES   512
#define S_SPATIAL 16384           // 16*32*32
#define ZQ_ELEMS  33554432        // 8*256*16384
#define OUT_LOSS  33554432
#define OUT_IDXB  33554433        // idx written as float here
#define OUT_PERP  (33554433 + 131072)

// Workspace layout (bytes) — only ~2.1 KB used (safe for any ws_size)
#define WS_LOSS   0               // double
#define WS_HIST   16              // int[512]
#define WS_E2     2064            // float[512]
#define WS_FIXED  2064            // bytes zeroed (loss + hist)

// ---------------------------------------------------------------------------
// Kernel 1: codebook squared norms s_e[k], numpy-pairwise replica.
__global__ __launch_bounds__(256) void e2_kernel(const float* __restrict__ e,
                                                 float* __restrict__ e2) {
    int k = blockIdx.x * 256 + threadIdx.x;
    if (k >= K_CODES) return;
    const float* row = e + (size_t)k * DIM;
    float half[2];
#pragma unroll
    for (int h = 0; h < 2; ++h) {
        const float* base = row + h * 128;
        float r[8];
#pragma unroll
        for (int j = 0; j < 8; ++j) {
            float v = base[j];
            r[j] = __fmul_rn(v, v);
        }
        for (int i = 8; i < 128; i += 8) {
#pragma unroll
            for (int j = 0; j < 8; ++j) {
                float v = base[i + j];
                r[j] = __fadd_rn(r[j], __fmul_rn(v, v));
            }
        }
        half[h] = __fadd_rn(__fadd_rn(__fadd_rn(r[0], r[1]), __fadd_rn(r[2], r[3])),
                            __fadd_rn(__fadd_rn(r[4], r[5]), __fadd_rn(r[6], r[7])));
    }
    e2[k] = __fadd_rn(half[0], half[1]);
}

// ---------------------------------------------------------------------------
// Kernel 1b: transpose codebook for pass1. Lane l owns codes k_c = c*64 + l,
// c=0..7. For dim d it reads eTq[d*512 + l*8 + c], i.e. 32 B per lane per d
// as two float4s; the wave reads 2 KB contiguous per d.
__global__ __launch_bounds__(256) void transpose_e(const float* __restrict__ e,
                                                   float* __restrict__ eTq) {
    int t = blockIdx.x * 256 + threadIdx.x;     // t = k*256 + d, coalesced read
    int k = t >> 8;
    int d = t & 255;
    float v = e[t];
    int c = k >> 6;
    int l = k & 63;
    eTq[(d << 9) + (l << 3) + c] = v;
}

// ---------------------------------------------------------------------------
// Kernel 1c: s_z[n] = numpy-pairwise sum of z[n,d]^2. Thread = position,
// lane-coalesced strided loads. Bit-exact: same tree/order as reference.
__global__ __launch_bounds__(256) void sz_kernel(const float* __restrict__ z,
                                                 float* __restrict__ sz) {
    int n = blockIdx.x * 256 + threadIdx.x;
    int b = n >> 14;
    int s = n & (S_SPATIAL - 1);
    const float* zp = z + (size_t)b * (DIM * S_SPATIAL) + s;
    float half[2];
#pragma unroll
    for (int h = 0; h < 2; ++h) {
        const float* base = zp + (size_t)(h * 128) * S_SPATIAL;
        float r[8];
#pragma unroll
        for (int j = 0; j < 8; ++j) {
            float v = base[(size_t)j * S_SPATIAL];
            r[j] = __fmul_rn(v, v);
        }
        for (int i = 8; i < 128; i += 8) {
#pragma unroll
            for (int j = 0; j < 8; ++j) {
                float v = base[(size_t)(i + j) * S_SPATIAL];
                r[j] = __fadd_rn(r[j], __fmul_rn(v, v));
            }
        }
        half[h] = __fadd_rn(__fadd_rn(__fadd_rn(r[0], r[1]), __fadd_rn(r[2], r[3])),
                            __fadd_rn(__fadd_rn(r[4], r[5]), __fadd_rn(r[6], r[7])));
    }
    sz[n] = __fadd_rn(half[0], half[1]);
}

// ---------------------------------------------------------------------------
// Kernel 2: distance + argmin. Block = 1 wave (64 lanes) x 16 positions.
// Lane owns C=8 codes (c*64 + lane, c=0..7) -> wave covers all 512 codes.
// z slice (256d x 16pos = 16 KB) staged in LDS; per d: 4 broadcast
// ds_read_b128 (uniform addr, conflict-free) + 2 coalesced float4 (eTq, L2)
// + 128 FMAs. Explicit 2-deep register pipeline (A/B buffers): loads for
// d+1/d+2 issue before the 128-FMA block for d (~256 cy), hiding LDS
// (~120 cy) and L2 (~200 cy) latency inside the wave. Per accumulator the
// FMA chain is ascending in d — bit-exact numpy replica (identical math to
// the round-4 PASSED kernel). Argmin: packed (dist_bits<<32|idx) u64 min
// over c (idx in low bits -> first-index ties), 64-lane butterfly; lane p
// keeps position p. Histogram fused into the tail.
__global__ __launch_bounds__(64, 2) void pass1_dist(const float* __restrict__ z,
                                                    const float* __restrict__ eTq,
                                                    const float* __restrict__ e2,
                                                    const float* __restrict__ sz,
                                                    float* __restrict__ idxf,
                                                    int* __restrict__ ghist) {
    const int lane = threadIdx.x;               // 0..63
    const int n0   = blockIdx.x << 4;           // 16 positions per block
    const int b    = n0 >> 14;
    const float* zb = z + (size_t)b * (DIM * S_SPATIAL) + (n0 & (S_SPATIAL - 1));

    __shared__ float zs[DIM][16];               // 16 KB

    // ---- cooperative z stage: 1024 float4s over 64 lanes ----
    for (int j = lane; j < 1024; j += 64) {
        int d  = j >> 2;
        int p4 = (j & 3) << 2;
        float4 v = *(const float4*)(zb + ((size_t)d << 14) + p4);
        *(float4*)(&zs[d][p4]) = v;
    }

    float szv = sz[n0 + (lane & 15)];           // lane p<16 holds sz[n0+p]

    float se[8];
#pragma unroll
    for (int c = 0; c < 8; ++c) se[c] = e2[(c << 6) + lane];

    float a0[16], a1[16], a2[16], a3[16], a4[16], a5[16], a6[16], a7[16];
#pragma unroll
    for (int p = 0; p < 16; ++p) {
        a0[p] = 0.f; a1[p] = 0.f; a2[p] = 0.f; a3[p] = 0.f;
        a4[p] = 0.f; a5[p] = 0.f; a6[p] = 0.f; a7[p] = 0.f;
    }

    __syncthreads();

    const float* ep = eTq + (lane << 3);

#define LOADZ(zv, d) do {                                        \
        *(float4*)((zv) +  0) = *(const float4*)(&zs[(d)][ 0]);  \
        *(float4*)((zv) +  4) = *(const float4*)(&zs[(d)][ 4]);  \
        *(float4*)((zv) +  8) = *(const float4*)(&zs[(d)][ 8]);  \
        *(float4*)((zv) + 12) = *(const float4*)(&zs[(d)][12]);  \
    } while (0)

#define LOADE(e0, e1, d) do {                                    \
        e0 = *(const float4*)(ep + ((size_t)(d) << 9));          \
        e1 = *(const float4*)(ep + ((size_t)(d) << 9) + 4);      \
    } while (0)

#define FMAS(zv, e0, e1) do {                                    \
        _Pragma("unroll")                                        \
        for (int p = 0; p < 16; ++p) {                           \
            float zp_ = (zv)[p];                                 \
            a0[p] = __fmaf_rn(zp_, (e0).x, a0[p]);               \
            a1[p] = __fmaf_rn(zp_, (e0).y, a1[p]);               \
            a2[p] = __fmaf_rn(zp_, (e0).z, a2[p]);               \
            a3[p] = __fmaf_rn(zp_, (e0).w, a3[p]);               \
            a4[p] = __fmaf_rn(zp_, (e1).x, a4[p]);               \
            a5[p] = __fmaf_rn(zp_, (e1).y, a5[p]);               \
            a6[p] = __fmaf_rn(zp_, (e1).z, a6[p]);               \
            a7[p] = __fmaf_rn(zp_, (e1).w, a7[p]);               \
        }                                                        \
    } while (0)

    // ---- pipelined main loop: FMAs on d overlap loads for d+2 ----
    float zvA[16], zvB[16];
    float4 eA0, eA1, eB0, eB1;
    LOADZ(zvA, 0); LOADE(eA0, eA1, 0);
    LOADZ(zvB, 1); LOADE(eB0, eB1, 1);
#pragma unroll 1
    for (int d = 0; d < DIM - 2; d += 2) {
        FMAS(zvA, eA0, eA1);                    // dim d   (ascending chain)
        LOADZ(zvA, d + 2); LOADE(eA0, eA1, d + 2);
        FMAS(zvB, eB0, eB1);                    // dim d+1
        LOADZ(zvB, d + 3); LOADE(eB0, eB1, d + 3);
    }
    FMAS(zvA, eA0, eA1);                        // dim 254
    FMAS(zvB, eB0, eB1);                        // dim 255

#undef LOADZ
#undef LOADE
#undef FMAS

    // ---- argmin: pack, in-lane min over c (ascending idx), 64-lane
    //      butterfly; lane p keeps position p; fused histogram ----
    unsigned long long myMin = 0xffffffffffffffffull;
#pragma unroll
    for (int p = 0; p < 16; ++p) {
        float szp = __shfl(szv, p);
        float d0 = __fsub_rn(__fadd_rn(szp, se[0]), __fmul_rn(2.0f, a0[p]));
        float d1 = __fsub_rn(__fadd_rn(szp, se[1]), __fmul_rn(2.0f, a1[p]));
        float d2 = __fsub_rn(__fadd_rn(szp, se[2]), __fmul_rn(2.0f, a2[p]));
        float d3 = __fsub_rn(__fadd_rn(szp, se[3]), __fmul_rn(2.0f, a3[p]));
        float d4 = __fsub_rn(__fadd_rn(szp, se[4]), __fmul_rn(2.0f, a4[p]));
        float d5 = __fsub_rn(__fadd_rn(szp, se[5]), __fmul_rn(2.0f, a5[p]));
        float d6 = __fsub_rn(__fadd_rn(szp, se[6]), __fmul_rn(2.0f, a6[p]));
        float d7 = __fsub_rn(__fadd_rn(szp, se[7]), __fmul_rn(2.0f, a7[p]));
        unsigned long long k0 = ((unsigned long long)__float_as_uint(d0) << 32) | (unsigned int)(lane);
        unsigned long long k1 = ((unsigned long long)__float_as_uint(d1) << 32) | (unsigned int)(lane + 64);
        unsigned long long k2 = ((unsigned long long)__float_as_uint(d2) << 32) | (unsigned int)(lane + 128);
        unsigned long long k3 = ((unsigned long long)__float_as_uint(d3) << 32) | (unsigned int)(lane + 192);
        unsigned long long k4 = ((unsigned long long)__float_as_uint(d4) << 32) | (unsigned int)(lane + 256);
        unsigned long long k5 = ((unsigned long long)__float_as_uint(d5) << 32) | (unsigned int)(lane + 320);
        unsigned long long k6 = ((unsigned long long)__float_as_uint(d6) << 32) | (unsigned int)(lane + 384);
        unsigned long long k7 = ((unsigned long long)__float_as_uint(d7) << 32) | (unsigned int)(lane + 448);
        unsigned long long m01 = k1 < k0 ? k1 : k0;
        unsigned long long m23 = k3 < k2 ? k3 : k2;
        unsigned long long m45 = k5 < k4 ? k5 : k4;
        unsigned long long m67 = k7 < k6 ? k7 : k6;
        unsigned long long mA = m23 < m01 ? m23 : m01;
        unsigned long long mB = m67 < m45 ? m67 : m45;
        unsigned long long kmin = mB < mA ? mB : mA;
#pragma unroll
        for (int off = 32; off; off >>= 1) {
            unsigned long long o = __shfl_xor(kmin, off);
            kmin = o < kmin ? o : kmin;
        }
        if (lane == p) myMin = kmin;
    }
    if (lane < 16) {
        int idx = (int)(unsigned int)(myMin & 0xffffffffull);
        idxf[n0 + lane] = (float)idx;
        atomicAdd(&ghist[idx], 1);
    }
}

// ---------------------------------------------------------------------------
// Kernel 4: gather z_q = fl(z + fl(e[idx]-z)) + loss accumulation (double).
__global__ __launch_bounds__(256) void gather_loss(const float* __restrict__ z,
                                                   const float* __restrict__ e,
                                                   const float* __restrict__ idxf,
                                                   float* __restrict__ out,
                                                   double* __restrict__ loss) {
    int t = blockIdx.x * 256 + threadIdx.x;   // 131072 threads total
    int b   = t >> 14;
    int r   = t & 16383;
    int dg  = r >> 12;                        // 0..3 -> d range [dg*64, dg*64+64)
    int sp  = (r & 4095) << 2;                // sp multiple of 4
    int n0  = (b << 14) + sp;

    int k0 = (int)idxf[n0 + 0];
    int k1 = (int)idxf[n0 + 1];
    int k2 = (int)idxf[n0 + 2];
    int k3 = (int)idxf[n0 + 3];
    const float* e0 = e + (size_t)k0 * DIM;
    const float* e1 = e + (size_t)k1 * DIM;
    const float* e2p = e + (size_t)k2 * DIM;
    const float* e3 = e + (size_t)k3 * DIM;

    const float* zb = z + ((size_t)b * DIM << 14) + sp;
    float* ob = out + ((size_t)b * DIM << 14) + sp;

    double acc = 0.0;
    int dend = dg * 64 + 64;
    for (int d0 = dg * 64; d0 < dend; d0 += 4) {
        float4 ev0 = *(const float4*)(e0 + d0);   // components: dd=0..3 for k0
        float4 ev1 = *(const float4*)(e1 + d0);
        float4 ev2 = *(const float4*)(e2p + d0);
        float4 ev3 = *(const float4*)(e3 + d0);
#pragma unroll
        for (int dd = 0; dd < 4; ++dd) {
            size_t off = ((size_t)(d0 + dd) << 14);
            float4 zv = *(const float4*)(zb + off);
            float ea = (dd == 0) ? ev0.x : (dd == 1) ? ev0.y : (dd == 2) ? ev0.z : ev0.w;
            float eb_ = (dd == 0) ? ev1.x : (dd == 1) ? ev1.y : (dd == 2) ? ev1.z : ev1.w;
            float ec = (dd == 0) ? ev2.x : (dd == 1) ? ev2.y : (dd == 2) ? ev2.z : ev2.w;
            float ed = (dd == 0) ? ev3.x : (dd == 1) ? ev3.y : (dd == 2) ? ev3.z : ev3.w;
            float d0f = __fsub_rn(ea, zv.x);
            float d1f = __fsub_rn(eb_, zv.y);
            float d2f = __fsub_rn(ec, zv.z);
            float d3f = __fsub_rn(ed, zv.w);
            float4 ov;
            ov.x = __fadd_rn(zv.x, d0f);
            ov.y = __fadd_rn(zv.y, d1f);
            ov.z = __fadd_rn(zv.z, d2f);
            ov.w = __fadd_rn(zv.w, d3f);
            *(float4*)(ob + off) = ov;
            acc += (double)d0f * (double)d0f;
            acc += (double)d1f * (double)d1f;
            acc += (double)d2f * (double)d2f;
            acc += (double)d3f * (double)d3f;
        }
    }
    // block reduce (4 waves)
    for (int off = 32; off; off >>= 1) acc += __shfl_down(acc, off);
    __shared__ double red[4];
    if ((threadIdx.x & 63) == 0) red[threadIdx.x >> 6] = acc;
    __syncthreads();
    if (threadIdx.x == 0) {
        double tsum = red[0] + red[1] + red[2] + red[3];
        atomicAdd(loss, tsum);
    }
}

// ---------------------------------------------------------------------------
// Kernel 5: finalize vq_loss and perplexity. 1 block, 512 threads.
__global__ __launch_bounds__(512) void finalize_kernel(const int* __restrict__ ghist,
                                                       const double* __restrict__ loss,
                                                       float* __restrict__ out) {
    int k = threadIdx.x;
    double p = (double)ghist[k] / (double)N_POS;
    double t = p * log(p + 1e-10);
    for (int off = 32; off; off >>= 1) t += __shfl_down(t, off);
    __shared__ double red[8];
    if ((k & 63) == 0) red[k >> 6] = t;
    __syncthreads();
    if (k == 0) {
        double sum = 0.0;
        for (int i = 0; i < 8; ++i) sum += red[i];
        double perp = exp(-sum);
        double mse  = (*loss) / (double)ZQ_ELEMS;
        out[OUT_LOSS] = (float)(1.25 * mse);   // codebook + 0.25*commit, same MSE
        out[OUT_PERP] = (float)perp;
    }
}

// ---------------------------------------------------------------------------
extern "C" void kernel_launch(void* const* d_in, const int* in_sizes, int n_in,
                              void* d_out, int out_size, void* d_ws, size_t ws_size,
                              hipStream_t stream) {
    const float* z = (const float*)d_in[0];
    const float* e = (const float*)d_in[1];
    float* out = (float*)d_out;
    char* ws = (char*)d_ws;

    double* loss  = (double*)(ws + WS_LOSS);
    int*    ghist = (int*)(ws + WS_HIST);
    float*  e2    = (float*)(ws + WS_E2);
    float*  idxf  = out + OUT_IDXB;

    // Scratch in the z_q output region (overwritten by gather_loss later,
    // which runs after all readers): eTq = 512 KB, sz = 512 KB.
    float* eTq = (float*)d_out;                     // 131072 floats
    float* szp = (float*)d_out + 131072;            // 131072 floats

    hipMemsetAsync(d_ws, 0, WS_FIXED, stream);      // loss + hist = 0

    e2_kernel      <<<2, 256, 0, stream>>>(e, e2);
    transpose_e    <<<512, 256, 0, stream>>>(e, eTq);
    sz_kernel      <<<N_POS / 256, 256, 0, stream>>>(z, szp);
    pass1_dist     <<<N_POS / 16, 64, 0, stream>>>(z, eTq, e2, szp, idxf, ghist);
    gather_loss    <<<N_POS / 256, 256, 0, stream>>>(z, e, idxf, out, loss);
    finalize_kernel<<<1, 512, 0, stream>>>(ghist, loss, out);
}

// Round 7
// 627.506 us; speedup vs baseline: 2.8764x; 1.0791x over previous
//
#include <hip/hip_runtime.h>
#include <math.h>

// Problem constants
#define N_POS     131072          // 8 * 16*32*32 positions
#define DIM       256
#define K_CODES   512
#define S_SPATIAL 16384           // 16*32*32
#define ZQ_ELEMS  33554432        // 8*256*16384
#define OUT_LOSS  33554432
#define OUT_IDXB  33554433        // idx written as float here
#define OUT_PERP  (33554433 + 131072)

// Workspace layout (bytes) — only ~2.1 KB used (safe for any ws_size)
#define WS_LOSS   0               // double
#define WS_HIST   16              // int[512]
#define WS_E2     2064            // float[512]
#define WS_FIXED  2064            // bytes zeroed (loss + hist)

typedef float sfloat16 __attribute__((ext_vector_type(16)));

// ---------------------------------------------------------------------------
// Kernel 1: codebook squared norms s_e[k], numpy-pairwise replica.
__global__ __launch_bounds__(256) void e2_kernel(const float* __restrict__ e,
                                                 float* __restrict__ e2) {
    int k = blockIdx.x * 256 + threadIdx.x;
    if (k >= K_CODES) return;
    const float* row = e + (size_t)k * DIM;
    float half[2];
#pragma unroll
    for (int h = 0; h < 2; ++h) {
        const float* base = row + h * 128;
        float r[8];
#pragma unroll
        for (int j = 0; j < 8; ++j) {
            float v = base[j];
            r[j] = __fmul_rn(v, v);
        }
        for (int i = 8; i < 128; i += 8) {
#pragma unroll
            for (int j = 0; j < 8; ++j) {
                float v = base[i + j];
                r[j] = __fadd_rn(r[j], __fmul_rn(v, v));
            }
        }
        half[h] = __fadd_rn(__fadd_rn(__fadd_rn(r[0], r[1]), __fadd_rn(r[2], r[3])),
                            __fadd_rn(__fadd_rn(r[4], r[5]), __fadd_rn(r[6], r[7])));
    }
    e2[k] = __fadd_rn(half[0], half[1]);
}

// ---------------------------------------------------------------------------
// Kernel 1b: transpose codebook for pass1. Lane l owns codes k_c = c*64 + l,
// c=0..7. For dim d it reads eTq[d*512 + l*8 + c], i.e. 32 B per lane per d
// as two float4s; the wave reads 2 KB contiguous per d.
__global__ __launch_bounds__(256) void transpose_e(const float* __restrict__ e,
                                                   float* __restrict__ eTq) {
    int t = blockIdx.x * 256 + threadIdx.x;     // t = k*256 + d, coalesced read
    int k = t >> 8;
    int d = t & 255;
    float v = e[t];
    int c = k >> 6;
    int l = k & 63;
    eTq[(d << 9) + (l << 3) + c] = v;
}

// ---------------------------------------------------------------------------
// Kernel 1c: s_z[n] = numpy-pairwise sum of z[n,d]^2. Thread = position,
// lane-coalesced strided loads. Bit-exact: same tree/order as reference.
__global__ __launch_bounds__(256) void sz_kernel(const float* __restrict__ z,
                                                 float* __restrict__ sz) {
    int n = blockIdx.x * 256 + threadIdx.x;
    int b = n >> 14;
    int s = n & (S_SPATIAL - 1);
    const float* zp = z + (size_t)b * (DIM * S_SPATIAL) + s;
    float half[2];
#pragma unroll
    for (int h = 0; h < 2; ++h) {
        const float* base = zp + (size_t)(h * 128) * S_SPATIAL;
        float r[8];
#pragma unroll
        for (int j = 0; j < 8; ++j) {
            float v = base[(size_t)j * S_SPATIAL];
            r[j] = __fmul_rn(v, v);
        }
        for (int i = 8; i < 128; i += 8) {
#pragma unroll
            for (int j = 0; j < 8; ++j) {
                float v = base[(size_t)(i + j) * S_SPATIAL];
                r[j] = __fadd_rn(r[j], __fmul_rn(v, v));
            }
        }
        half[h] = __fadd_rn(__fadd_rn(__fadd_rn(r[0], r[1]), __fadd_rn(r[2], r[3])),
                            __fadd_rn(__fadd_rn(r[4], r[5]), __fadd_rn(r[6], r[7])));
    }
    sz[n] = __fadd_rn(half[0], half[1]);
}

// ---------------------------------------------------------------------------
// Kernel 2: distance + argmin. Block = 1 wave x 16 positions; lane owns C=8
// codes (c*64 + lane) -> wave covers all 512 codes. z comes through the
// SCALAR pipe: the 16 positions at dim d are one contiguous, wave-uniform
// 64 B line. Per 2 dims, ONE fused asm block does
//   s_load_dwordx16 zA ; s_load_dwordx16 zB ; s_waitcnt lgkmcnt(0)
// so the async-SMEM window is closed INSIDE the asm — the register
// allocator can never copy/touch pending SGPRs (v6's failure mode).
// Latency is hidden by TLP (3 waves/SIMD), not by an open-window pipeline.
// z costs 0 VGPR and 0 LDS; FMAs read z as the single legal SGPR operand.
// e via two coalesced float4 per lane per d (L2-hot, vmcnt-covered).
// Per accumulator the FMA chain ascends d — bit-exact numpy replica of the
// round-4 PASSED math. Argmin tail: packed (dist_bits<<32|idx) u64 min over
// c (idx low bits -> first-index ties), 64-lane butterfly; lane p keeps
// position p. Histogram fused.
__global__ __launch_bounds__(64, 3) void pass1_dist(const float* __restrict__ z,
                                                    const float* __restrict__ eTq,
                                                    const float* __restrict__ e2,
                                                    const float* __restrict__ sz,
                                                    float* __restrict__ idxf,
                                                    int* __restrict__ ghist) {
    const int lane = threadIdx.x;               // 0..63
    const int n0   = blockIdx.x << 4;           // 16 positions per block
    const int b    = n0 >> 14;
    const unsigned long long zbase =
        (unsigned long long)(const void*)(z + (size_t)b * (DIM * S_SPATIAL)
                                            + (n0 & (S_SPATIAL - 1)));

    float szv = sz[n0 + (lane & 15)];           // lane p<16 holds sz[n0+p]

    float se[8];
#pragma unroll
    for (int c = 0; c < 8; ++c) se[c] = e2[(c << 6) + lane];

    float a0[16], a1[16], a2[16], a3[16], a4[16], a5[16], a6[16], a7[16];
#pragma unroll
    for (int p = 0; p < 16; ++p) {
        a0[p] = 0.f; a1[p] = 0.f; a2[p] = 0.f; a3[p] = 0.f;
        a4[p] = 0.f; a5[p] = 0.f; a6[p] = 0.f; a7[p] = 0.f;
    }

    const float* ep = eTq + (lane << 3);

#define FMAS(zv, e0, e1) do {                                    \
        _Pragma("unroll")                                        \
        for (int p = 0; p < 16; ++p) {                           \
            a0[p] = __fmaf_rn((zv)[p], (e0).x, a0[p]);           \
            a1[p] = __fmaf_rn((zv)[p], (e0).y, a1[p]);           \
            a2[p] = __fmaf_rn((zv)[p], (e0).z, a2[p]);           \
            a3[p] = __fmaf_rn((zv)[p], (e0).w, a3[p]);           \
            a4[p] = __fmaf_rn((zv)[p], (e1).x, a4[p]);           \
            a5[p] = __fmaf_rn((zv)[p], (e1).y, a5[p]);           \
            a6[p] = __fmaf_rn((zv)[p], (e1).z, a6[p]);           \
            a7[p] = __fmaf_rn((zv)[p], (e1).w, a7[p]);           \
        }                                                        \
    } while (0)

#pragma unroll 1
    for (int d = 0; d < DIM; d += 2) {
        // e-loads issue first; their vmcnt latency is covered by the SMEM
        // stall inside the fused z-load block below.
        float4 e0 = *(const float4*)(ep + ((size_t)d << 9));
        float4 e1 = *(const float4*)(ep + ((size_t)d << 9) + 4);
        float4 f0 = *(const float4*)(ep + ((size_t)(d + 1) << 9));
        float4 f1 = *(const float4*)(ep + ((size_t)(d + 1) << 9) + 4);

        sfloat16 zA, zB;                         // live in SGPRs only
        unsigned long long addrA = zbase + ((unsigned long long)d << 16);
        unsigned long long addrB = addrA + 65536ull;
        asm volatile("s_load_dwordx16 %0, %2, 0x0\n\t"
                     "s_load_dwordx16 %1, %3, 0x0\n\t"
                     "s_waitcnt lgkmcnt(0)"
                     : "=&s"(zA), "=&s"(zB)
                     : "s"(addrA), "s"(addrB));

        FMAS(zA, e0, e1);                        // dim d   (ascending chain)
        FMAS(zB, f0, f1);                        // dim d+1
    }
#undef FMAS

    // ---- argmin: pack, in-lane min over c (ascending idx), 64-lane
    //      butterfly; lane p keeps position p; fused histogram ----
    unsigned long long myMin = 0xffffffffffffffffull;
#pragma unroll
    for (int p = 0; p < 16; ++p) {
        float szp = __shfl(szv, p);
        float d0 = __fsub_rn(__fadd_rn(szp, se[0]), __fmul_rn(2.0f, a0[p]));
        float d1 = __fsub_rn(__fadd_rn(szp, se[1]), __fmul_rn(2.0f, a1[p]));
        float d2 = __fsub_rn(__fadd_rn(szp, se[2]), __fmul_rn(2.0f, a2[p]));
        float d3 = __fsub_rn(__fadd_rn(szp, se[3]), __fmul_rn(2.0f, a3[p]));
        float d4 = __fsub_rn(__fadd_rn(szp, se[4]), __fmul_rn(2.0f, a4[p]));
        float d5 = __fsub_rn(__fadd_rn(szp, se[5]), __fmul_rn(2.0f, a5[p]));
        float d6 = __fsub_rn(__fadd_rn(szp, se[6]), __fmul_rn(2.0f, a6[p]));
        float d7 = __fsub_rn(__fadd_rn(szp, se[7]), __fmul_rn(2.0f, a7[p]));
        unsigned long long k0 = ((unsigned long long)__float_as_uint(d0) << 32) | (unsigned int)(lane);
        unsigned long long k1 = ((unsigned long long)__float_as_uint(d1) << 32) | (unsigned int)(lane + 64);
        unsigned long long k2 = ((unsigned long long)__float_as_uint(d2) << 32) | (unsigned int)(lane + 128);
        unsigned long long k3 = ((unsigned long long)__float_as_uint(d3) << 32) | (unsigned int)(lane + 192);
        unsigned long long k4 = ((unsigned long long)__float_as_uint(d4) << 32) | (unsigned int)(lane + 256);
        unsigned long long k5 = ((unsigned long long)__float_as_uint(d5) << 32) | (unsigned int)(lane + 320);
        unsigned long long k6 = ((unsigned long long)__float_as_uint(d6) << 32) | (unsigned int)(lane + 384);
        unsigned long long k7 = ((unsigned long long)__float_as_uint(d7) << 32) | (unsigned int)(lane + 448);
        unsigned long long m01 = k1 < k0 ? k1 : k0;
        unsigned long long m23 = k3 < k2 ? k3 : k2;
        unsigned long long m45 = k5 < k4 ? k5 : k4;
        unsigned long long m67 = k7 < k6 ? k7 : k6;
        unsigned long long mA = m23 < m01 ? m23 : m01;
        unsigned long long mB = m67 < m45 ? m67 : m45;
        unsigned long long kmin = mB < mA ? mB : mA;
#pragma unroll
        for (int off = 32; off; off >>= 1) {
            unsigned long long o = __shfl_xor(kmin, off);
            kmin = o < kmin ? o : kmin;
        }
        if (lane == p) myMin = kmin;
    }
    if (lane < 16) {
        int idx = (int)(unsigned int)(myMin & 0xffffffffull);
        idxf[n0 + lane] = (float)idx;
        atomicAdd(&ghist[idx], 1);
    }
}

// ---------------------------------------------------------------------------
// Kernel 4: gather z_q = fl(z + fl(e[idx]-z)) + loss accumulation (double).
__global__ __launch_bounds__(256) void gather_loss(const float* __restrict__ z,
                                                   const float* __restrict__ e,
                                                   const float* __restrict__ idxf,
                                                   float* __restrict__ out,
                                                   double* __restrict__ loss) {
    int t = blockIdx.x * 256 + threadIdx.x;   // 131072 threads total
    int b   = t >> 14;
    int r   = t & 16383;
    int dg  = r >> 12;                        // 0..3 -> d range [dg*64, dg*64+64)
    int sp  = (r & 4095) << 2;                // sp multiple of 4
    int n0  = (b << 14) + sp;

    int k0 = (int)idxf[n0 + 0];
    int k1 = (int)idxf[n0 + 1];
    int k2 = (int)idxf[n0 + 2];
    int k3 = (int)idxf[n0 + 3];
    const float* e0 = e + (size_t)k0 * DIM;
    const float* e1 = e + (size_t)k1 * DIM;
    const float* e2p = e + (size_t)k2 * DIM;
    const float* e3 = e + (size_t)k3 * DIM;

    const float* zb = z + ((size_t)b * DIM << 14) + sp;
    float* ob = out + ((size_t)b * DIM << 14) + sp;

    double acc = 0.0;
    int dend = dg * 64 + 64;
    for (int d0 = dg * 64; d0 < dend; d0 += 4) {
        float4 ev0 = *(const float4*)(e0 + d0);   // components: dd=0..3 for k0
        float4 ev1 = *(const float4*)(e1 + d0);
        float4 ev2 = *(const float4*)(e2p + d0);
        float4 ev3 = *(const float4*)(e3 + d0);
#pragma unroll
        for (int dd = 0; dd < 4; ++dd) {
            size_t off = ((size_t)(d0 + dd) << 14);
            float4 zv = *(const float4*)(zb + off);
            float ea = (dd == 0) ? ev0.x : (dd == 1) ? ev0.y : (dd == 2) ? ev0.z : ev0.w;
            float eb_ = (dd == 0) ? ev1.x : (dd == 1) ? ev1.y : (dd == 2) ? ev1.z : ev1.w;
            float ec = (dd == 0) ? ev2.x : (dd == 1) ? ev2.y : (dd == 2) ? ev2.z : ev2.w;
            float ed = (dd == 0) ? ev3.x : (dd == 1) ? ev3.y : (dd == 2) ? ev3.z : ev3.w;
            float d0f = __fsub_rn(ea, zv.x);
            float d1f = __fsub_rn(eb_, zv.y);
            float d2f = __fsub_rn(ec, zv.z);
            float d3f = __fsub_rn(ed, zv.w);
            float4 ov;
            ov.x = __fadd_rn(zv.x, d0f);
            ov.y = __fadd_rn(zv.y, d1f);
            ov.z = __fadd_rn(zv.z, d2f);
            ov.w = __fadd_rn(zv.w, d3f);
            *(float4*)(ob + off) = ov;
            acc += (double)d0f * (double)d0f;
            acc += (double)d1f * (double)d1f;
            acc += (double)d2f * (double)d2f;
            acc += (double)d3f * (double)d3f;
        }
    }
    // block reduce (4 waves)
    for (int off = 32; off; off >>= 1) acc += __shfl_down(acc, off);
    __shared__ double red[4];
    if ((threadIdx.x & 63) == 0) red[threadIdx.x >> 6] = acc;
    __syncthreads();
    if (threadIdx.x == 0) {
        double tsum = red[0] + red[1] + red[2] + red[3];
        atomicAdd(loss, tsum);
    }
}

// ---------------------------------------------------------------------------
// Kernel 5: finalize vq_loss and perplexity. 1 block, 512 threads.
__global__ __launch_bounds__(512) void finalize_kernel(const int* __restrict__ ghist,
                                                       const double* __restrict__ loss,
                                                       float* __restrict__ out) {
    int k = threadIdx.x;
    double p = (double)ghist[k] / (double)N_POS;
    double t = p * log(p + 1e-10);
    for (int off = 32; off; off >>= 1) t += __shfl_down(t, off);
    __shared__ double red[8];
    if ((k & 63) == 0) red[k >> 6] = t;
    __syncthreads();
    if (k == 0) {
        double sum = 0.0;
        for (int i = 0; i < 8; ++i) sum += red[i];
        double perp = exp(-sum);
        double mse  = (*loss) / (double)ZQ_ELEMS;
        out[OUT_LOSS] = (float)(1.25 * mse);   // codebook + 0.25*commit, same MSE
        out[OUT_PERP] = (float)perp;
    }
}

// ---------------------------------------------------------------------------
extern "C" void kernel_launch(void* const* d_in, const int* in_sizes, int n_in,
                              void* d_out, int out_size, void* d_ws, size_t ws_size,
                              hipStream_t stream) {
    const float* z = (const float*)d_in[0];
    const float* e = (const float*)d_in[1];
    float* out = (float*)d_out;
    char* ws = (char*)d_ws;

    double* loss  = (double*)(ws + WS_LOSS);
    int*    ghist = (int*)(ws + WS_HIST);
    float*  e2    = (float*)(ws + WS_E2);
    float*  idxf  = out + OUT_IDXB;

    // Scratch in the z_q output region (overwritten by gather_loss later,
    // which runs after all readers): eTq = 512 KB, sz = 512 KB.
    float* eTq = (float*)d_out;                     // 131072 floats
    float* szp = (float*)d_out + 131072;            // 131072 floats

    hipMemsetAsync(d_ws, 0, WS_FIXED, stream);      // loss + hist = 0

    e2_kernel      <<<2, 256, 0, stream>>>(e, e2);
    transpose_e    <<<512, 256, 0, stream>>>(e, eTq);
    sz_kernel      <<<N_POS / 256, 256, 0, stream>>>(z, szp);
    pass1_dist     <<<N_POS / 16, 64, 0, stream>>>(z, eTq, e2, szp, idxf, ghist);
    gather_loss    <<<N_POS / 256, 256, 0, stream>>>(z, e, idxf, out, loss);
    finalize_kernel<<<1, 512, 0, stream>>>(ghist, loss, out);
}

// Round 9
// 625.554 us; speedup vs baseline: 2.8853x; 1.0031x over previous
//
#include <hip/hip_runtime.h>
#include <math.h>

// Problem constants
#define N_POS     131072          // 8 * 16*32*32 positions
#define DIM       256
#define K_CODES   512
#define S_SPATIAL 16384           // 16*32*32
#define ZQ_ELEMS  33554432        // 8*256*16384
#define OUT_LOSS  33554432
#define OUT_IDXB  33554433        // idx written as float here
#define OUT_PERP  (33554433 + 131072)

// Workspace layout (bytes) — only ~2.1 KB used (safe for any ws_size)
#define WS_LOSS   0               // double
#define WS_HIST   16              // int[512]
#define WS_E2     2064            // float[512]
#define WS_FIXED  2064            // bytes zeroed (loss + hist)

typedef float sfloat16 __attribute__((ext_vector_type(16)));

// ---------------------------------------------------------------------------
// Kernel 1: codebook squared norms s_e[k], numpy-pairwise replica.
__global__ __launch_bounds__(256) void e2_kernel(const float* __restrict__ e,
                                                 float* __restrict__ e2) {
    int k = blockIdx.x * 256 + threadIdx.x;
    if (k >= K_CODES) return;
    const float* row = e + (size_t)k * DIM;
    float half[2];
#pragma unroll
    for (int h = 0; h < 2; ++h) {
        const float* base = row + h * 128;
        float r[8];
#pragma unroll
        for (int j = 0; j < 8; ++j) {
            float v = base[j];
            r[j] = __fmul_rn(v, v);
        }
        for (int i = 8; i < 128; i += 8) {
#pragma unroll
            for (int j = 0; j < 8; ++j) {
                float v = base[i + j];
                r[j] = __fadd_rn(r[j], __fmul_rn(v, v));
            }
        }
        half[h] = __fadd_rn(__fadd_rn(__fadd_rn(r[0], r[1]), __fadd_rn(r[2], r[3])),
                            __fadd_rn(__fadd_rn(r[4], r[5]), __fadd_rn(r[6], r[7])));
    }
    e2[k] = __fadd_rn(half[0], half[1]);
}

// ---------------------------------------------------------------------------
// Kernel 1b: transpose codebook for pass1. Lane l owns codes k_c = c*64 + l,
// c=0..7. For dim d it reads eTq[d*512 + l*8 + c], i.e. 32 B per lane per d
// as two float4s; the wave reads 2 KB contiguous per d.
__global__ __launch_bounds__(256) void transpose_e(const float* __restrict__ e,
                                                   float* __restrict__ eTq) {
    int t = blockIdx.x * 256 + threadIdx.x;     // t = k*256 + d, coalesced read
    int k = t >> 8;
    int d = t & 255;
    float v = e[t];
    int c = k >> 6;
    int l = k & 63;
    eTq[(d << 9) + (l << 3) + c] = v;
}

// ---------------------------------------------------------------------------
// Kernel 1c: s_z[n] = numpy-pairwise sum of z[n,d]^2. Thread = position,
// lane-coalesced strided loads. Bit-exact: same tree/order as reference.
__global__ __launch_bounds__(256) void sz_kernel(const float* __restrict__ z,
                                                 float* __restrict__ sz) {
    int n = blockIdx.x * 256 + threadIdx.x;
    int b = n >> 14;
    int s = n & (S_SPATIAL - 1);
    const float* zp = z + (size_t)b * (DIM * S_SPATIAL) + s;
    float half[2];
#pragma unroll
    for (int h = 0; h < 2; ++h) {
        const float* base = zp + (size_t)(h * 128) * S_SPATIAL;
        float r[8];
#pragma unroll
        for (int j = 0; j < 8; ++j) {
            float v = base[(size_t)j * S_SPATIAL];
            r[j] = __fmul_rn(v, v);
        }
        for (int i = 8; i < 128; i += 8) {
#pragma unroll
            for (int j = 0; j < 8; ++j) {
                float v = base[(size_t)(i + j) * S_SPATIAL];
                r[j] = __fadd_rn(r[j], __fmul_rn(v, v));
            }
        }
        half[h] = __fadd_rn(__fadd_rn(__fadd_rn(r[0], r[1]), __fadd_rn(r[2], r[3])),
                            __fadd_rn(__fadd_rn(r[4], r[5]), __fadd_rn(r[6], r[7])));
    }
    sz[n] = __fadd_rn(half[0], half[1]);
}

// ---------------------------------------------------------------------------
// Kernel 2: distance + argmin. Block = 1 wave x 16 positions; lane owns C=8
// codes (c*64 + lane) -> wave covers all 512 codes. z comes through the
// SCALAR pipe: 16 positions at dim d = one wave-uniform 64 B line. Per FOUR
// dims, ONE fused asm block issues 4x s_load_dwordx16 (imm offsets 0x0,
// 0x10000, 0x20000, 0x30000 — dim stride is 64 KB) and closes with
// s_waitcnt lgkmcnt(0). The async-SMEM window never spans C code (v6's
// failure mode); the ~250 cy stall is amortized over 1024 cy of FMAs
// (duty 0.67 -> 0.80 vs v7's 2-dim blocks). e-loads use uniform-base +
// per-lane-offset addressing -> saddr-form global_load_dwordx4 with SALU
// base bumps (minimal VALU); they issue before the z-wait, which covers
// their L2 latency. z costs 0 VGPR / 0 LDS; FMAs read z as the one legal
// SGPR operand. Per accumulator the FMA chain ascends d — bit-exact numpy
// replica of the round-7 PASSED math. Argmin tail unchanged: packed
// (dist_bits<<32|idx) u64 min over c, 64-lane butterfly, first-index ties;
// histogram fused.
__global__ __launch_bounds__(64, 3) void pass1_dist(const float* __restrict__ z,
                                                    const float* __restrict__ eTq,
                                                    const float* __restrict__ e2,
                                                    const float* __restrict__ sz,
                                                    float* __restrict__ idxf,
                                                    int* __restrict__ ghist) {
    const int lane = threadIdx.x;               // 0..63
    const int n0   = blockIdx.x << 4;           // 16 positions per block
    const int b    = n0 >> 14;
    const unsigned long long zbase =
        (unsigned long long)(const void*)(z + (size_t)b * (DIM * S_SPATIAL)
                                            + (n0 & (S_SPATIAL - 1)));

    float szv = sz[n0 + (lane & 15)];           // lane p<16 holds sz[n0+p]

    float se[8];
#pragma unroll
    for (int c = 0; c < 8; ++c) se[c] = e2[(c << 6) + lane];

    float a0[16], a1[16], a2[16], a3[16], a4[16], a5[16], a6[16], a7[16];
#pragma unroll
    for (int p = 0; p < 16; ++p) {
        a0[p] = 0.f; a1[p] = 0.f; a2[p] = 0.f; a3[p] = 0.f;
        a4[p] = 0.f; a5[p] = 0.f; a6[p] = 0.f; a7[p] = 0.f;
    }

    const int eoff = lane << 3;                 // float offset within a dim row

#define FMAS(zv, e0, e1) do {                                    \
        _Pragma("unroll")                                        \
        for (int p = 0; p < 16; ++p) {                           \
            a0[p] = __fmaf_rn((zv)[p], (e0).x, a0[p]);           \
            a1[p] = __fmaf_rn((zv)[p], (e0).y, a1[p]);           \
            a2[p] = __fmaf_rn((zv)[p], (e0).z, a2[p]);           \
            a3[p] = __fmaf_rn((zv)[p], (e0).w, a3[p]);           \
            a4[p] = __fmaf_rn((zv)[p], (e1).x, a4[p]);           \
            a5[p] = __fmaf_rn((zv)[p], (e1).y, a5[p]);           \
            a6[p] = __fmaf_rn((zv)[p], (e1).z, a6[p]);           \
            a7[p] = __fmaf_rn((zv)[p], (e1).w, a7[p]);           \
        }                                                        \
    } while (0)

#pragma unroll 1
    for (int d = 0; d < DIM; d += 4) {
        // e-loads: uniform base + lane offset -> saddr form, SALU bumps.
        const float* eb = eTq + ((size_t)d << 9);
        float4 e0 = *(const float4*)(eb + eoff);
        float4 e1 = *(const float4*)(eb + eoff + 4);
        float4 f0 = *(const float4*)(eb + eoff + 512);
        float4 f1 = *(const float4*)(eb + eoff + 516);
        float4 g0 = *(const float4*)(eb + eoff + 1024);
        float4 g1 = *(const float4*)(eb + eoff + 1028);
        float4 h0 = *(const float4*)(eb + eoff + 1536);
        float4 h1 = *(const float4*)(eb + eoff + 1540);

        sfloat16 zA, zB, zC, zD;                 // live in SGPRs only
        unsigned long long addr = zbase + ((unsigned long long)d << 16);
        asm volatile("s_load_dwordx16 %0, %4, 0x0\n\t"
                     "s_load_dwordx16 %1, %4, 0x10000\n\t"
                     "s_load_dwordx16 %2, %4, 0x20000\n\t"
                     "s_load_dwordx16 %3, %4, 0x30000\n\t"
                     "s_waitcnt lgkmcnt(0)"
                     : "=&s"(zA), "=&s"(zB), "=&s"(zC), "=&s"(zD)
                     : "s"(addr));

        FMAS(zA, e0, e1);                        // dim d   (ascending chain)
        FMAS(zB, f0, f1);                        // dim d+1
        FMAS(zC, g0, g1);                        // dim d+2
        FMAS(zD, h0, h1);                        // dim d+3
    }
#undef FMAS

    // ---- argmin: pack, in-lane min over c (ascending idx), 64-lane
    //      butterfly; lane p keeps position p; fused histogram ----
    unsigned long long myMin = 0xffffffffffffffffull;
#pragma unroll
    for (int p = 0; p < 16; ++p) {
        float szp = __shfl(szv, p);
        float d0 = __fsub_rn(__fadd_rn(szp, se[0]), __fmul_rn(2.0f, a0[p]));
        float d1 = __fsub_rn(__fadd_rn(szp, se[1]), __fmul_rn(2.0f, a1[p]));
        float d2 = __fsub_rn(__fadd_rn(szp, se[2]), __fmul_rn(2.0f, a2[p]));
        float d3 = __fsub_rn(__fadd_rn(szp, se[3]), __fmul_rn(2.0f, a3[p]));
        float d4 = __fsub_rn(__fadd_rn(szp, se[4]), __fmul_rn(2.0f, a4[p]));
        float d5 = __fsub_rn(__fadd_rn(szp, se[5]), __fmul_rn(2.0f, a5[p]));
        float d6 = __fsub_rn(__fadd_rn(szp, se[6]), __fmul_rn(2.0f, a6[p]));
        float d7 = __fsub_rn(__fadd_rn(szp, se[7]), __fmul_rn(2.0f, a7[p]));
        unsigned long long k0 = ((unsigned long long)__float_as_uint(d0) << 32) | (unsigned int)(lane);
        unsigned long long k1 = ((unsigned long long)__float_as_uint(d1) << 32) | (unsigned int)(lane + 64);
        unsigned long long k2 = ((unsigned long long)__float_as_uint(d2) << 32) | (unsigned int)(lane + 128);
        unsigned long long k3 = ((unsigned long long)__float_as_uint(d3) << 32) | (unsigned int)(lane + 192);
        unsigned long long k4 = ((unsigned long long)__float_as_uint(d4) << 32) | (unsigned int)(lane + 256);
        unsigned long long k5 = ((unsigned long long)__float_as_uint(d5) << 32) | (unsigned int)(lane + 320);
        unsigned long long k6 = ((unsigned long long)__float_as_uint(d6) << 32) | (unsigned int)(lane + 384);
        unsigned long long k7 = ((unsigned long long)__float_as_uint(d7) << 32) | (unsigned int)(lane + 448);
        unsigned long long m01 = k1 < k0 ? k1 : k0;
        unsigned long long m23 = k3 < k2 ? k3 : k2;
        unsigned long long m45 = k5 < k4 ? k5 : k4;
        unsigned long long m67 = k7 < k6 ? k7 : k6;
        unsigned long long mA = m23 < m01 ? m23 : m01;
        unsigned long long mB = m67 < m45 ? m67 : m45;
        unsigned long long kmin = mB < mA ? mB : mA;
#pragma unroll
        for (int off = 32; off; off >>= 1) {
            unsigned long long o = __shfl_xor(kmin, off);
            kmin = o < kmin ? o : kmin;
        }
        if (lane == p) myMin = kmin;
    }
    if (lane < 16) {
        int idx = (int)(unsigned int)(myMin & 0xffffffffull);
        idxf[n0 + lane] = (float)idx;
        atomicAdd(&ghist[idx], 1);
    }
}

// ---------------------------------------------------------------------------
// Kernel 4: gather z_q = fl(z + fl(e[idx]-z)) + loss accumulation (double).
__global__ __launch_bounds__(256) void gather_loss(const float* __restrict__ z,
                                                   const float* __restrict__ e,
                                                   const float* __restrict__ idxf,
                                                   float* __restrict__ out,
                                                   double* __restrict__ loss) {
    int t = blockIdx.x * 256 + threadIdx.x;   // 131072 threads total
    int b   = t >> 14;
    int r   = t & 16383;
    int dg  = r >> 12;                        // 0..3 -> d range [dg*64, dg*64+64)
    int sp  = (r & 4095) << 2;                // sp multiple of 4
    int n0  = (b << 14) + sp;

    int k0 = (int)idxf[n0 + 0];
    int k1 = (int)idxf[n0 + 1];
    int k2 = (int)idxf[n0 + 2];
    int k3 = (int)idxf[n0 + 3];
    const float* e0 = e + (size_t)k0 * DIM;
    const float* e1 = e + (size_t)k1 * DIM;
    const float* e2p = e + (size_t)k2 * DIM;
    const float* e3 = e + (size_t)k3 * DIM;

    const float* zb = z + ((size_t)b * DIM << 14) + sp;
    float* ob = out + ((size_t)b * DIM << 14) + sp;

    double acc = 0.0;
    int dend = dg * 64 + 64;
    for (int d0 = dg * 64; d0 < dend; d0 += 4) {
        float4 ev0 = *(const float4*)(e0 + d0);   // components: dd=0..3 for k0
        float4 ev1 = *(const float4*)(e1 + d0);
        float4 ev2 = *(const float4*)(e2p + d0);
        float4 ev3 = *(const float4*)(e3 + d0);
#pragma unroll
        for (int dd = 0; dd < 4; ++dd) {
            size_t off = ((size_t)(d0 + dd) << 14);
            float4 zv = *(const float4*)(zb + off);
            float ea = (dd == 0) ? ev0.x : (dd == 1) ? ev0.y : (dd == 2) ? ev0.z : ev0.w;
            float eb_ = (dd == 0) ? ev1.x : (dd == 1) ? ev1.y : (dd == 2) ? ev1.z : ev1.w;
            float ec = (dd == 0) ? ev2.x : (dd == 1) ? ev2.y : (dd == 2) ? ev2.z : ev2.w;
            float ed = (dd == 0) ? ev3.x : (dd == 1) ? ev3.y : (dd == 2) ? ev3.z : ev3.w;
            float d0f = __fsub_rn(ea, zv.x);
            float d1f = __fsub_rn(eb_, zv.y);
            float d2f = __fsub_rn(ec, zv.z);
            float d3f = __fsub_rn(ed, zv.w);
            float4 ov;
            ov.x = __fadd_rn(zv.x, d0f);
            ov.y = __fadd_rn(zv.y, d1f);
            ov.z = __fadd_rn(zv.z, d2f);
            ov.w = __fadd_rn(zv.w, d3f);
            *(float4*)(ob + off) = ov;
            acc += (double)d0f * (double)d0f;
            acc += (double)d1f * (double)d1f;
            acc += (double)d2f * (double)d2f;
            acc += (double)d3f * (double)d3f;
        }
    }
    // block reduce (4 waves)
    for (int off = 32; off; off >>= 1) acc += __shfl_down(acc, off);
    __shared__ double red[4];
    if ((threadIdx.x & 63) == 0) red[threadIdx.x >> 6] = acc;
    __syncthreads();
    if (threadIdx.x == 0) {
        double tsum = red[0] + red[1] + red[2] + red[3];
        atomicAdd(loss, tsum);
    }
}

// ---------------------------------------------------------------------------
// Kernel 5: finalize vq_loss and perplexity. 1 block, 512 threads.
__global__ __launch_bounds__(512) void finalize_kernel(const int* __restrict__ ghist,
                                                       const double* __restrict__ loss,
                                                       float* __restrict__ out) {
    int k = threadIdx.x;
    double p = (double)ghist[k] / (double)N_POS;
    double t = p * log(p + 1e-10);
    for (int off = 32; off; off >>= 1) t += __shfl_down(t, off);
    __shared__ double red[8];
    if ((k & 63) == 0) red[k >> 6] = t;
    __syncthreads();
    if (k == 0) {
        double sum = 0.0;
        for (int i = 0; i < 8; ++i) sum += red[i];
        double perp = exp(-sum);
        double mse  = (*loss) / (double)ZQ_ELEMS;
        out[OUT_LOSS] = (float)(1.25 * mse);   // codebook + 0.25*commit, same MSE
        out[OUT_PERP] = (float)perp;
    }
}

// ---------------------------------------------------------------------------
extern "C" void kernel_launch(void* const* d_in, const int* in_sizes, int n_in,
                              void* d_out, int out_size, void* d_ws, size_t ws_size,
                              hipStream_t stream) {
    const float* z = (const float*)d_in[0];
    const float* e = (const float*)d_in[1];
    float* out = (float*)d_out;
    char* ws = (char*)d_ws;

    double* loss  = (double*)(ws + WS_LOSS);
    int*    ghist = (int*)(ws + WS_HIST);
    float*  e2    = (float*)(ws + WS_E2);
    float*  idxf  = out + OUT_IDXB;

    // Scratch in the z_q output region (overwritten by gather_loss later,
    // which runs after all readers): eTq = 512 KB, sz = 512 KB.
    float* eTq = (float*)d_out;                     // 131072 floats
    float* szp = (float*)d_out + 131072;            // 131072 floats

    hipMemsetAsync(d_ws, 0, WS_FIXED, stream);      // loss + hist = 0

    e2_kernel      <<<2, 256, 0, stream>>>(e, e2);
    transpose_e    <<<512, 256, 0, stream>>>(e, eTq);
    sz_kernel      <<<N_POS / 256, 256, 0, stream>>>(z, szp);
    pass1_dist     <<<N_POS / 16, 64, 0, stream>>>(z, eTq, e2, szp, idxf, ghist);
    gather_loss    <<<N_POS / 256, 256, 0, stream>>>(z, e, idxf, out, loss);
    finalize_kernel<<<1, 512, 0, stream>>>(ghist, loss, out);
}